// Round 2
// baseline (805.436 us; speedup 1.0000x reference)
//
#include <hip/hip_runtime.h>
#include <math.h>

#define HDIM 2048
#define SLEN 4096
#define VOC  50257
#define NB_LOG 1024   // blocks for k_logits (4 waves each -> 4096 row-waves)

// ---------- helpers ----------
__device__ __forceinline__ float dot4(float4 a, float4 b) {
  return a.x * b.x + a.y * b.y + a.z * b.z + a.w * b.w;
}
__device__ __forceinline__ float wave_sum(float v) {
#pragma unroll
  for (int off = 32; off > 0; off >>= 1) v += __shfl_xor(v, off, 64);
  return v;
}
__device__ __forceinline__ float wave_max(float v) {
#pragma unroll
  for (int off = 32; off > 0; off >>= 1) v = fmaxf(v, __shfl_xor(v, off, 64));
  return v;
}

// ---------- K1: GRU cell. One block per output element j. ----------
__global__ __launch_bounds__(256) void k_gru(
    const int* __restrict__ input_id, const float* __restrict__ hidden,
    const float* __restrict__ emb, const float* __restrict__ W_ih,
    const float* __restrict__ W_hh, const float* __restrict__ b_ih,
    const float* __restrict__ b_hh, float* __restrict__ h_new) {
  const int j = blockIdx.x;
  const int tid = threadIdx.x;
  const float4* x4 = (const float4*)(emb + (size_t)input_id[0] * HDIM);
  const float4* h4 = (const float4*)hidden;
  const float4* wir = (const float4*)(W_ih + (size_t)j * HDIM);
  const float4* wiz = (const float4*)(W_ih + (size_t)(HDIM + j) * HDIM);
  const float4* win = (const float4*)(W_ih + (size_t)(2 * HDIM + j) * HDIM);
  const float4* whr = (const float4*)(W_hh + (size_t)j * HDIM);
  const float4* whz = (const float4*)(W_hh + (size_t)(HDIM + j) * HDIM);
  const float4* whn = (const float4*)(W_hh + (size_t)(2 * HDIM + j) * HDIM);

  float a0 = 0.f, a1 = 0.f, a2 = 0.f, a3 = 0.f, a4 = 0.f, a5 = 0.f;
#pragma unroll 2
  for (int t = tid; t < HDIM / 4; t += 256) {
    float4 xv = x4[t], hv = h4[t];
    a0 += dot4(wir[t], xv);
    a1 += dot4(wiz[t], xv);
    a2 += dot4(win[t], xv);
    a3 += dot4(whr[t], hv);
    a4 += dot4(whz[t], hv);
    a5 += dot4(whn[t], hv);
  }
  a0 = wave_sum(a0); a1 = wave_sum(a1); a2 = wave_sum(a2);
  a3 = wave_sum(a3); a4 = wave_sum(a4); a5 = wave_sum(a5);

  __shared__ float red[4][6];
  const int wid = tid >> 6, lane = tid & 63;
  if (lane == 0) {
    red[wid][0] = a0; red[wid][1] = a1; red[wid][2] = a2;
    red[wid][3] = a3; red[wid][4] = a4; red[wid][5] = a5;
  }
  __syncthreads();
  if (tid == 0) {
    float ir = 0, iz = 0, inn = 0, hr = 0, hz = 0, hn = 0;
#pragma unroll
    for (int w = 0; w < 4; ++w) {
      ir += red[w][0]; iz += red[w][1]; inn += red[w][2];
      hr += red[w][3]; hz += red[w][4]; hn += red[w][5];
    }
    ir += b_ih[j]; iz += b_ih[HDIM + j]; inn += b_ih[2 * HDIM + j];
    hr += b_hh[j]; hz += b_hh[HDIM + j]; hn += b_hh[2 * HDIM + j];
    const float r = 1.f / (1.f + expf(-(ir + hr)));
    const float z = 1.f / (1.f + expf(-(iz + hz)));
    const float n = tanhf(inn + r * hn);
    h_new[j] = (1.f - z) * n + z * hidden[j];
  }
}

// ---------- K2a: scores[s] = enc[s,:] . h_new  (one wave per row) ----------
__global__ __launch_bounds__(256) void k_scores(
    const float* __restrict__ enc, const float* __restrict__ h_new,
    float* __restrict__ scores) {
  const int row = blockIdx.x * 4 + (threadIdx.x >> 6);
  const int lane = threadIdx.x & 63;
  const float4* e4 = (const float4*)(enc + (size_t)row * HDIM);
  const float4* h4 = (const float4*)h_new;
  float acc = 0.f;
#pragma unroll
  for (int i = 0; i < (HDIM / 4) / 64; ++i) {  // 8 iters
    const int t = lane + i * 64;
    acc += dot4(e4[t], h4[t]);
  }
  acc = wave_sum(acc);
  if (lane == 0) scores[row] = acc;
}

// ---------- K2b: softmax over S in-place; also zero ctx ----------
__global__ __launch_bounds__(1024) void k_softmax(float* __restrict__ attn,
                                                  float* __restrict__ ctx) {
  __shared__ float sred[16];
  const int tid = threadIdx.x;
  const int wid = tid >> 6, lane = tid & 63;
  float v[4];
#pragma unroll
  for (int i = 0; i < 4; ++i) v[i] = attn[tid + i * 1024];
  float m = fmaxf(fmaxf(v[0], v[1]), fmaxf(v[2], v[3]));
  m = wave_max(m);
  if (lane == 0) sred[wid] = m;
  __syncthreads();
  if (tid < 64) {
    float t = (lane < 16) ? sred[lane] : -INFINITY;
    t = wave_max(t);
    if (lane == 0) sred[0] = t;
  }
  __syncthreads();
  m = sred[0];
  __syncthreads();  // everyone has read sred[0] before reuse

  float s = 0.f;
#pragma unroll
  for (int i = 0; i < 4; ++i) {
    v[i] = expf(v[i] - m);
    s += v[i];
  }
  s = wave_sum(s);
  if (lane == 0) sred[wid] = s;
  __syncthreads();
  if (tid < 64) {
    float t = (lane < 16) ? sred[lane] : 0.f;
    t = wave_sum(t);
    if (lane == 0) sred[0] = t;
  }
  __syncthreads();
  const float inv = 1.f / sred[0];
#pragma unroll
  for (int i = 0; i < 4; ++i) attn[tid + i * 1024] = v[i] * inv;
  // zero ctx for the atomic accumulation kernel
  ctx[tid] = 0.f;
  ctx[tid + 1024] = 0.f;
}

// ---------- K2c: ctx[c] = sum_s attn[s]*enc[s,c]  (col-parallel, S-split) ----------
__global__ __launch_bounds__(256) void k_ctx(const float* __restrict__ enc,
                                             const float* __restrict__ attn,
                                             float* __restrict__ ctx) {
  const int c = blockIdx.x * 256 + threadIdx.x;
  const int s0 = blockIdx.y * 64;
  float acc = 0.f;
#pragma unroll 4
  for (int s = s0; s < s0 + 64; ++s) acc += attn[s] * enc[(size_t)s * HDIM + c];
  atomicAdd(&ctx[c], acc);
}

// ---------- K3: comb = tanh(W_comb @ cat(ctx,h_new) + b)  (one wave/row) ----------
__global__ __launch_bounds__(256) void k_comb(
    const float* __restrict__ W_comb, const float* __restrict__ ctx,
    const float* __restrict__ h_new, const float* __restrict__ b_comb,
    float* __restrict__ comb) {
  const int row = blockIdx.x * 4 + (threadIdx.x >> 6);
  const int lane = threadIdx.x & 63;
  const float4* w4 = (const float4*)(W_comb + (size_t)row * (2 * HDIM));
  const float4* c4 = (const float4*)ctx;
  const float4* h4 = (const float4*)h_new;
  float acc = 0.f;
#pragma unroll
  for (int i = 0; i < 8; ++i) {
    const int t = lane + i * 64;
    acc += dot4(w4[t], c4[t]);
  }
#pragma unroll
  for (int i = 0; i < 8; ++i) {
    const int t = lane + i * 64;
    acc += dot4(w4[512 + t], h4[t]);
  }
  acc = wave_sum(acc);
  if (lane == 0) comb[row] = tanhf(acc + b_comb[row]);
}

// ---------- K4a: logits = W_out @ comb + b_out, with per-block online
//            (max, sumexp) partials for the log_softmax. Grid-stride rows. ----------
__global__ __launch_bounds__(256) void k_logits(
    const float* __restrict__ W_out, const float* __restrict__ comb,
    const float* __restrict__ b_out, float* __restrict__ logits,
    float* __restrict__ pm, float* __restrict__ ps) {
  const int wid = threadIdx.x >> 6, lane = threadIdx.x & 63;
  const int wave0 = blockIdx.x * 4 + wid;  // global wave id in [0, 4096)
  const float4* c4 = (const float4*)comb;

  float m = -INFINITY, s = 0.f;  // per-wave online LSE (uniform across lanes)
  for (int row = wave0; row < VOC; row += NB_LOG * 4) {
    const float4* w4 = (const float4*)(W_out + (size_t)row * HDIM);
    float acc = 0.f;
#pragma unroll
    for (int i = 0; i < (HDIM / 4) / 64; ++i) {  // 8 iters
      const int t = lane + i * 64;
      acc += dot4(w4[t], c4[t]);
    }
    acc = wave_sum(acc);               // result in all lanes
    const float l = acc + b_out[row];  // row is wave-uniform
    if (lane == 0) logits[row] = l;
    const float mn = fmaxf(m, l);
    s = s * expf(m - mn) + expf(l - mn);  // m=-inf first iter: exp(-inf)=0, 0*0=0
    m = mn;
  }

  __shared__ float sm[4], ss[4];
  if (lane == 0) { sm[wid] = m; ss[wid] = s; }
  __syncthreads();
  if (threadIdx.x == 0) {
    float M = sm[0], S = ss[0];
#pragma unroll
    for (int w = 1; w < 4; ++w) {
      const float mn = fmaxf(M, sm[w]);
      S = S * expf(M - mn) + ss[w] * expf(sm[w] - mn);
      M = mn;
    }
    pm[blockIdx.x] = M;
    ps[blockIdx.x] = S;
  }
}

// ---------- K4b: combine 1024 block partials -> lse; log_probs = logits - lse ----------
__global__ __launch_bounds__(256) void k_final(const float* __restrict__ logits,
                                               const float* __restrict__ pm,
                                               const float* __restrict__ ps,
                                               float* __restrict__ out) {
  const int tid = threadIdx.x;
  const int wid = tid >> 6, lane = tid & 63;

  // per-thread: combine 4 partials (all partials are valid: every block had rows)
  float m = pm[tid], s = ps[tid];
#pragma unroll
  for (int i = 1; i < 4; ++i) {
    const float mo = pm[tid + i * 256], so = ps[tid + i * 256];
    const float mn = fmaxf(m, mo);
    s = s * expf(m - mn) + so * expf(mo - mn);
    m = mn;
  }
  // wave combine
#pragma unroll
  for (int off = 32; off > 0; off >>= 1) {
    const float mo = __shfl_xor(m, off, 64), so = __shfl_xor(s, off, 64);
    const float mn = fmaxf(m, mo);
    s = s * expf(m - mn) + so * expf(mo - mn);
    m = mn;
  }
  __shared__ float sm[4], ss[4];
  if (lane == 0) { sm[wid] = m; ss[wid] = s; }
  __syncthreads();
  // all threads combine the 4 wave results identically (uniform, cheap)
  float M = sm[0], S = ss[0];
#pragma unroll
  for (int w = 1; w < 4; ++w) {
    const float mn = fmaxf(M, sm[w]);
    S = S * expf(M - mn) + ss[w] * expf(sm[w] - mn);
    M = mn;
  }
  const float lse = M + logf(S);

  const int v = blockIdx.x * 256 + tid;
  if (v < VOC) out[v] = logits[v] - lse;
}

extern "C" void kernel_launch(void* const* d_in, const int* in_sizes, int n_in,
                              void* d_out, int out_size, void* d_ws,
                              size_t ws_size, hipStream_t stream) {
  const int* input_id = (const int*)d_in[0];
  const float* hidden = (const float*)d_in[1];
  const float* enc    = (const float*)d_in[2];
  const float* emb    = (const float*)d_in[3];
  const float* W_ih   = (const float*)d_in[4];
  const float* W_hh   = (const float*)d_in[5];
  const float* b_ih   = (const float*)d_in[6];
  const float* b_hh   = (const float*)d_in[7];
  const float* W_comb = (const float*)d_in[8];
  const float* b_comb = (const float*)d_in[9];
  const float* W_out  = (const float*)d_in[10];
  const float* b_out  = (const float*)d_in[11];

  float* out = (float*)d_out;
  float* log_probs = out;              // [V]
  float* h_new = out + VOC;            // [H]
  float* attn = out + VOC + HDIM;      // [S]

  float* ws = (float*)d_ws;
  float* ctx    = ws;                      // [H]
  float* comb   = ws + HDIM;               // [H]
  float* logits = ws + 2 * HDIM;           // [V]
  float* pm     = ws + 2 * HDIM + VOC;     // [NB_LOG]
  float* ps     = pm + NB_LOG;             // [NB_LOG]

  k_gru<<<HDIM, 256, 0, stream>>>(input_id, hidden, emb, W_ih, W_hh, b_ih,
                                  b_hh, h_new);
  k_scores<<<SLEN / 4, 256, 0, stream>>>(enc, h_new, attn);
  k_softmax<<<1, 1024, 0, stream>>>(attn, ctx);
  k_ctx<<<dim3(HDIM / 256, SLEN / 64), 256, 0, stream>>>(enc, attn, ctx);
  k_comb<<<HDIM / 4, 256, 0, stream>>>(W_comb, ctx, h_new, b_comb, comb);
  k_logits<<<NB_LOG, 256, 0, stream>>>(W_out, comb, b_out, logits, pm, ps);
  k_final<<<(VOC + 255) / 256, 256, 0, stream>>>(logits, pm, ps, log_probs);
}